// Round 15
// baseline (219.258 us; speedup 1.0000x reference)
//
#include <hip/hip_runtime.h>
#include <hip/hip_bf16.h>
#include <cstdint>

// Problem dims (fixed): B=2, S=2048, E=1024, H=16, D=64
#define PB 2
#define PS 2048
#define PE 1024
#define PH 16
#define PD 64

typedef __attribute__((ext_vector_type(8))) short short8;
typedef __attribute__((ext_vector_type(8))) ushort u16x8;
typedef __attribute__((ext_vector_type(4))) float f32x4;

static __device__ __forceinline__ float bf2f(ushort u) {
  return __uint_as_float(((unsigned)u) << 16);
}
static __device__ __forceinline__ ushort f2bf(float f) {
  unsigned u = __float_as_uint(f);
  u += 0x7fffu + ((u >> 16) & 1u);   // RNE
  return (ushort)(u >> 16);
}
// packed f32x2 -> bf16x2 (v_cvt_pk_bf16_f32 on gfx950 via HIP API)
static __device__ __forceinline__ unsigned pkbf(float a, float b) {
  __hip_bfloat162 h = __float22bfloat162_rn(make_float2(a, b));
  return *reinterpret_cast<unsigned*>(&h);
}
static __device__ __forceinline__ u16x8 cvt8(f32x4 a, f32x4 b) {
  union { unsigned u[4]; u16x8 v; } r;
  r.u[0] = pkbf(a[0], a[1]); r.u[1] = pkbf(a[2], a[3]);
  r.u[2] = pkbf(b[0], b[1]); r.u[3] = pkbf(b[2], b[3]);
  return r.v;
}

// CK-idiom async global->LDS 16B copy. LDS dest must be wave-uniform base.
static __device__ __forceinline__ void async16(void* lds, const void* g) {
  __attribute__((address_space(3))) unsigned* l =
      reinterpret_cast<__attribute__((address_space(3))) unsigned*>(
          reinterpret_cast<uintptr_t>(lds));
  const __attribute__((address_space(1))) unsigned* gp =
      reinterpret_cast<const __attribute__((address_space(1))) unsigned*>(
          reinterpret_cast<uintptr_t>(g));
  __builtin_amdgcn_global_load_lds(gp, l, 16, 0, 0);
}

// ---------------------------------------------------------------------------
// fp32 -> bf16 pre-conversion (x tensors + weights). blockIdx.y selects.
// 16 elems/thread.
// ---------------------------------------------------------------------------
__global__ __launch_bounds__(256)
void cvt_kernel(const float* __restrict__ s0, const float* __restrict__ s1,
                const float* __restrict__ s2, const float* __restrict__ s3,
                const float* __restrict__ s4, const float* __restrict__ s5,
                const float* __restrict__ s6,
                ushort* d0, ushort* d1, ushort* d2, ushort* d3, ushort* d4,
                ushort* d5, ushort* d6) {
  const int t = blockIdx.y;
  const float* src = t == 0 ? s0 : t == 1 ? s1 : t == 2 ? s2 : t == 3 ? s3
                   : t == 4 ? s4 : t == 5 ? s5 : s6;
  ushort* dst = t == 0 ? d0 : t == 1 ? d1 : t == 2 ? d2 : t == 3 ? d3
              : t == 4 ? d4 : t == 5 ? d5 : d6;
  const size_t n = (t < 3) ? (size_t)4194304 : (size_t)1048576;
  const size_t i0 = ((size_t)blockIdx.x * 256 + threadIdx.x) * 16;
  if (i0 >= n) return;
  const f32x4 a = *(const f32x4*)(src + i0);
  const f32x4 b = *(const f32x4*)(src + i0 + 4);
  const f32x4 c = *(const f32x4*)(src + i0 + 8);
  const f32x4 d = *(const f32x4*)(src + i0 + 12);
  *(u16x8*)(dst + i0) = cvt8(a, b);
  *(u16x8*)(dst + i0 + 8) = cvt8(c, d);
}

// ---------------------------------------------------------------------------
// GEMM core, bf16 A: BM=BN=128, BK=32, 4 waves 2x2, DEPTH-STAGE PIPELINE.
// Loop t: stage(t+DEPTH-1) -> s_waitcnt vmcnt(ahead*4) -> s_barrier ->
// compute(t) -> s_barrier. DEPTH=3 == R8-verified 8/4/0 sequence.
// DEPTH=3: qkv (48KB, 3 blocks/CU). DEPTH=5: outproj (80KB, 1 block/CU,
// depth does all the latency hiding). NOTE (R9): BM=64 regressed.
// NOTE (R11): K-phase rotation regressed (FETCH 37->86MB) — co-resident
// blocks' identical K order IS the L2 sharing mechanism; never desync.
// SWAP=false: acc[i][j] = C[m=x-rows i][n=W-rows j] (normal).
// SWAP=true : acc[i][j] = C[m=W-rows j][n=x-rows i] (transposed output).
// ---------------------------------------------------------------------------
template <bool SWAP, int DEPTH>
__device__ __forceinline__ void gemm_core(const ushort* __restrict__ A,
                                          const ushort* __restrict__ W,
                                          int m0, int n0,
                                          ushort* As, ushort* Bs,
                                          f32x4 acc[4][4]) {
  const int tid  = threadIdx.x;
  const int wave = tid >> 6;
  const int lane = tid & 63;
  const int quad = lane >> 4;
  const int lrow = lane & 15;
  const int wm = wave >> 1;
  const int wn = wave & 1;
  const int row0 = tid >> 2;
  const int kc8  = (tid & 3) * 8;

  auto stage = [&](int buf, int kt) {
    ushort* Ab = As + buf * 4096;
    ushort* Bb = Bs + buf * 4096;
    async16(Ab + (size_t)wave * 512,        A + (size_t)(m0 + row0)      * PE + kt + kc8);
    async16(Ab + 2048 + (size_t)wave * 512, A + (size_t)(m0 + row0 + 64) * PE + kt + kc8);
    async16(Bb + (size_t)wave * 512,        W + (size_t)(n0 + row0)      * PE + kt + kc8);
    async16(Bb + 2048 + (size_t)wave * 512, W + (size_t)(n0 + row0 + 64) * PE + kt + kc8);
  };

#pragma unroll
  for (int s = 0; s < DEPTH - 1; ++s) stage(s, s * 32);
  int cb = 0;                       // compute buffer = t % DEPTH (address-only)

  for (int t = 0; t < 32; ++t) {
    if (t + DEPTH - 1 < 32) {
      const int sb = (cb == 0) ? DEPTH - 1 : cb - 1;   // (t+DEPTH-1) % DEPTH
      stage(sb, (t + DEPTH - 1) * 32);
    }
    const int ahead = ((t + DEPTH - 1 < 32) ? DEPTH - 1 : 31 - t);
    if      (ahead >= 4) asm volatile("s_waitcnt vmcnt(16)" ::: "memory");
    else if (ahead == 3) asm volatile("s_waitcnt vmcnt(12)" ::: "memory");
    else if (ahead == 2) asm volatile("s_waitcnt vmcnt(8)"  ::: "memory");
    else if (ahead == 1) asm volatile("s_waitcnt vmcnt(4)"  ::: "memory");
    else                 asm volatile("s_waitcnt vmcnt(0)"  ::: "memory");
    __builtin_amdgcn_s_barrier();   // all waves' t-loads in LDS

    const ushort* Ab = As + cb * 4096;
    const ushort* Bb = Bs + cb * 4096;
    short8 af[4], bf[4];
#pragma unroll
    for (int i = 0; i < 4; ++i) {
      af[i] = *(const short8*)(Ab + (wm * 64 + i * 16 + lrow) * 32 + quad * 8);
      bf[i] = *(const short8*)(Bb + (wn * 64 + i * 16 + lrow) * 32 + quad * 8);
    }
#pragma unroll
    for (int i = 0; i < 4; ++i)
#pragma unroll
      for (int j = 0; j < 4; ++j) {
        if (SWAP)
          acc[i][j] = __builtin_amdgcn_mfma_f32_16x16x32_bf16(bf[j], af[i], acc[i][j], 0, 0, 0);
        else
          acc[i][j] = __builtin_amdgcn_mfma_f32_16x16x32_bf16(af[i], bf[j], acc[i][j], 0, 0, 0);
      }
    __builtin_amdgcn_s_barrier();   // reads of buf cb done -> stage may reuse
    cb = (cb == DEPTH - 1) ? 0 : cb + 1;
  }
}

// ---------------------------------------------------------------------------
// Fused QKV projection (bf16 x, bf16 W). Q,K -> [B,H,S,D]; V -> [B,H,D,S']
// where S' applies the PV-native key permutation pi within each 64-key block
// (R14, correctness harness-verified): pi(k) = (k&0x23)|((k&0xC)<<1)|
// ((k&0x10)>>2). R15: the pi-scatter is ABSORBED IN LDS — acc values are
// ds_written to a [128 d][128 pos] tile at permuted positions (gemm LDS is
// dead post-core; granule-XOR swizzle), then re-read row-wise and stored as
// 256B-contiguous global runs (R14's direct pi-store broke lane coalescing
// into 8B runs, +3 µs). Q/K branch unchanged.
// Grid (x=m0, y=which*8+n0): n0-siblings share A-strip on one XCD's L2.
// ---------------------------------------------------------------------------
__global__ __launch_bounds__(256)
void qkv_kernel(const ushort* __restrict__ q, const ushort* __restrict__ k,
                const ushort* __restrict__ v,
                const ushort* __restrict__ Wq, const ushort* __restrict__ Wk,
                const ushort* __restrict__ Wv,
                const float* __restrict__ bq, const float* __restrict__ bk,
                const float* __restrict__ bv,
                ushort* __restrict__ qh, ushort* __restrict__ kh,
                ushort* __restrict__ vt) {
  __shared__ __align__(16) ushort SM[2 * 3 * 128 * 32];   // 48KB
  ushort* As = SM;
  ushort* Bs = SM + 3 * 128 * 32;
  const int which = blockIdx.y >> 3;
  const int n0 = (blockIdx.y & 7) * 128;
  const int m0 = blockIdx.x * 128;
  const ushort* A  = which == 0 ? q  : (which == 1 ? k  : v);
  const ushort* W  = which == 0 ? Wq : (which == 1 ? Wk : Wv);
  const float* bi  = which == 0 ? bq : (which == 1 ? bk : bv);

  const int lane = threadIdx.x & 63;
  const int wave = threadIdx.x >> 6;
  const int quad = lane >> 4, lrow = lane & 15;
  const int wm = wave >> 1, wn = wave & 1;

  f32x4 acc[4][4] = {};
  if (which == 2) {
    gemm_core<true, 3>(A, W, m0, n0, As, Bs, acc);
    // acc[i][j]: C[m=W-row tile j][n=x-row tile i]; col=lane&15 -> x-row,
    // row=quad*4+r -> W-row (d-col).
    // Phase 1: scatter into LDS [local_d][pi(local_s)] (XOR-swizzled
    // granules). gemm_core's final barrier guarantees LDS is free.
#pragma unroll
    for (int j = 0; j < 4; ++j) {
#pragma unroll
      for (int i = 0; i < 4; ++i) {
        const int ls = wm * 64 + i * 16 + lrow;      // local_s 0..127
        const int k6 = ls & 63;                      // pi within 64-key block
        const int spp = (ls & 64) | (k6 & 0x23) | ((k6 & 0x0C) << 1) |
                        ((k6 & 0x10) >> 2);
#pragma unroll
        for (int r = 0; r < 4; ++r) {
          const int ld = wn * 64 + j * 16 + quad * 4 + r;  // local_d 0..127
          const int pos = (((spp >> 3) ^ (ld & 7)) << 3) | (spp & 7);
          SM[ld * 128 + pos] = f2bf(acc[i][j][r] + bi[n0 + ld]);
        }
      }
    }
    __syncthreads();
    // Phase 2: coalesced store — each d-row is 256B contiguous in vt.
    const int b = m0 >> 11, sbase = m0 & 2047;   // 128-blocks don't straddle b
    const int l16 = threadIdx.x & 15;
    const int r0  = threadIdx.x >> 4;            // 0..15
#pragma unroll
    for (int p = 0; p < 8; ++p) {
      const int ld = p * 16 + r0;
      const int dcol = n0 + ld;
      const int h = dcol >> 6, d = dcol & 63;
      const u16x8 vreg = *(const u16x8*)&SM[ld * 128 + ((l16 ^ (ld & 7)) << 3)];
      *(u16x8*)(vt + ((size_t)((b << 4) + h) << 17) + ((size_t)d << 11) +
                sbase + l16 * 8) = vreg;
    }
  } else {
    gemm_core<false, 3>(A, W, m0, n0, As, Bs, acc);
    ushort* Out = which == 0 ? qh : kh;
#pragma unroll
    for (int j = 0; j < 4; ++j) {
      const int col = n0 + wn * 64 + j * 16 + lrow;          // n in [0,1024)
      const float bias = bi[col];
      const int h = col >> 6, d = col & 63;
#pragma unroll
      for (int i = 0; i < 4; ++i)
#pragma unroll
        for (int r = 0; r < 4; ++r) {
          const int row = m0 + wm * 64 + i * 16 + quad * 4 + r;  // m in [0,4096)
          const int b = row >> 11, s = row & 2047;
          Out[((size_t)((b << 4) + h) << 17) + ((size_t)s << 6) + d] =
              f2bf(acc[i][j][r] + bias);
        }
    }
  }
}

// ---------------------------------------------------------------------------
// Output projection: out = ctx @ Wo^T + bo -> fp32 [4096,1024].
// Grid (x=m0 32, y=n0 8) = 1 block/CU -> DEPTH=5 (80KB LDS) does all the
// latency hiding in-block. BM=128 kept (R9: BM=64 regressed).
// ---------------------------------------------------------------------------
__global__ __launch_bounds__(256)
void outproj_kernel(const ushort* __restrict__ ctx, const ushort* __restrict__ Wo,
                    const float* __restrict__ bo, float* __restrict__ out) {
  __shared__ __align__(16) ushort As[5 * 128 * 32];
  __shared__ __align__(16) ushort Bs[5 * 128 * 32];
  const int n0 = blockIdx.y * 128;
  const int m0 = blockIdx.x * 128;

  f32x4 acc[4][4] = {};
  gemm_core<false, 5>(ctx, Wo, m0, n0, As, Bs, acc);

  const int lane = threadIdx.x & 63;
  const int wave = threadIdx.x >> 6;
  const int quad = lane >> 4, lrow = lane & 15;
  const int wm = wave >> 1, wn = wave & 1;
#pragma unroll
  for (int j = 0; j < 4; ++j) {
    const int col = n0 + wn * 64 + j * 16 + lrow;
    const float bias = bo[col];
#pragma unroll
    for (int i = 0; i < 4; ++i)
#pragma unroll
      for (int r = 0; r < 4; ++r) {
        const int row = m0 + wm * 64 + i * 16 + quad * 4 + r;
        out[((size_t)row << 10) + col] = acc[i][j][r] + bias;
      }
  }
}

// ---------------------------------------------------------------------------
// MFMA causal flash attention — R14 version (P LDS round-trip deleted;
// harness-verified): qkv stores V^T with pi-permuted key columns, so the PV
// B-fragment equals the QK output register order after cvt_pk — P goes regs
// -> pkbf -> MFMA B-operand directly. No Ps buffer, 16 LDS ops/wave-tile.
// q-split, 4 blocks/CU, async K/V staging (pre-swizzled source, linear LDS
// dest, double-buffered, one __syncthreads per tile), NO setprio (m190/R9).
// Balance perm (R3), l via ones-MFMA (R3), SOFF in C-init (R2).
// ---------------------------------------------------------------------------
#define SW_IDX(r, g) (((r) << 6) + ((((g) ^ ((r) & 7))) << 3))
#define QSCALE 0.180336879f   /* 1/sqrt(64) * log2(e) */
#define SOFF 24.0f            /* static softmax offset (log2 domain) */

__global__ __launch_bounds__(256)
void attn_kernel(const ushort* __restrict__ qh, const ushort* __restrict__ kh,
                 const ushort* __restrict__ vt, ushort* __restrict__ ctx) {
  __shared__ __align__(16) ushort Ks[2][4096];
  __shared__ __align__(16) ushort Vs[2][4096];
  const int tid  = threadIdx.x;
  const int wave = tid >> 6;
  const int lane = tid & 63;
  const int quad = lane >> 4;
  const int lrow = lane & 15;
  const int bh = blockIdx.x, b = bh >> 4, h = bh & 15;
  const size_t base = (size_t)bh << 17;     // bh * S * D
  const int pr   = wave * 16 + lrow;        // this lane's q row in tile

  // balance permutation: CU-resident {y,y+8,y+16,y+24} sum to 62
  const int y  = blockIdx.y;
  const int qb = (y < 8) ? 31 - y : (y < 16) ? y - 8 : (y < 24) ? 39 - y : y - 16;
  const int q0 = qb * 64;

  // async staging geometry: wave w stages rows w*16..w*16+15 of K and V^T
  // (2 async16 calls each, 8 rows/call). Linear LDS dest + swizzled source.
  const int w16  = wave * 16;
  const int rl   = lane >> 3;                       // row within 8-row stripe
  const int gsw  = ((lane & 7) ^ rl) << 3;          // swizzled src granule
  auto stageKV = [&](int buf, int kt) {
    const ushort* k0 = kh + base + (size_t)(kt * 64 + w16 + rl) * 64 + gsw;
    const ushort* k1 = kh + base + (size_t)(kt * 64 + w16 + 8 + rl) * 64 + gsw;
    async16(&Ks[buf][w16 << 6],       k0);
    async16(&Ks[buf][(w16 + 8) << 6], k1);
    const ushort* v0 = vt + base + (size_t)(w16 + rl) * 2048 + kt * 64 + gsw;
    const ushort* v1 = vt + base + (size_t)(w16 + 8 + rl) * 2048 + kt * 64 + gsw;
    async16(&Vs[buf][w16 << 6],       v0);
    async16(&Vs[buf][(w16 + 8) << 6], v1);
  };

  // Q B-fragments in registers, scaled by 1/sqrt(D)*log2(e)
  short8 qf0, qf1;
  {
    const ushort* qp = qh + base + (size_t)(q0 + pr) * 64 + quad * 8;
    const u16x8 a = *(const u16x8*)qp;
    const u16x8 c = *(const u16x8*)(qp + 32);
#pragma unroll
    for (int j = 0; j < 8; ++j) {
      qf0[j] = (short)f2bf(bf2f(a[j]) * QSCALE);
      qf1[j] = (short)f2bf(bf2f(c[j]) * QSCALE);
    }
  }

  // all-ones bf16 A-fragment for the l row-sum MFMA
  short8 ones;
#pragma unroll
  for (int j = 0; j < 8; ++j) ones[j] = (short)0x3F80;

  f32x4 o_acc[4] = {};
  f32x4 lacc = {};   // P row-sum accumulator (every slot holds the same sum)

  stageKV(0, 0);
  __syncthreads();   // prologue drain: tile 0 resident

  for (int kt = 0; kt <= qb; ++kt) {
    const int buf = kt & 1;
    if (kt < qb) stageKV(buf ^ 1, kt + 1);   // in flight during compute

    // S^T = mfma(K, Q): lane -> q=pr, keys nt*16+quad*4+r; C-init = -SOFF
    f32x4 st[4];
#pragma unroll
    for (int nt = 0; nt < 4; ++nt) {
      const int r = nt * 16 + lrow;
      const short8 kb0 = *(const short8*)&Ks[buf][SW_IDX(r, quad)];
      const short8 kb1 = *(const short8*)&Ks[buf][SW_IDX(r, quad + 4)];
      st[nt] = (f32x4){-SOFF, -SOFF, -SOFF, -SOFF};
      st[nt] = __builtin_amdgcn_mfma_f32_16x16x32_bf16(kb0, qf0, st[nt], 0, 0, 0);
      st[nt] = __builtin_amdgcn_mfma_f32_16x16x32_bf16(kb1, qf1, st[nt], 0, 0, 0);
    }

    if (kt == qb) {    // causal mask on diagonal tile (local coords)
#pragma unroll
      for (int nt = 0; nt < 4; ++nt)
#pragma unroll
        for (int r = 0; r < 4; ++r)
          if (nt * 16 + quad * 4 + r > pr) st[nt][r] = -1e30f;
    }

    // softmax + pack DIRECTLY into PV B-fragments (PV-native key order via
    // qkv's pi-permuted V^T): pb.v[0] = {st[0],st[1]}, pb.v[1] = {st[2],
    // st[3]} — no LDS, no cross-lane.
    union { unsigned u[8]; short8 v[2]; } pb;
#pragma unroll
    for (int nt = 0; nt < 4; ++nt) {
      const float p0 = exp2f(st[nt][0]);
      const float p1 = exp2f(st[nt][1]);
      const float p2 = exp2f(st[nt][2]);
      const float p3 = exp2f(st[nt][3]);
      pb.u[nt * 2]     = pkbf(p0, p1);
      pb.u[nt * 2 + 1] = pkbf(p2, p3);
    }
    const short8 pa0 = pb.v[0];
    const short8 pa1 = pb.v[1];

    // l row-sum on the MFMA pipe: A=ones -> out[q][*] = sum_k P[q][k]
    lacc = __builtin_amdgcn_mfma_f32_16x16x32_bf16(ones, pa0, lacc, 0, 0, 0);
    lacc = __builtin_amdgcn_mfma_f32_16x16x32_bf16(ones, pa1, lacc, 0, 0, 0);

    // PV: O^T = mfma(V^T, P): lane -> q=pr, d = nt*16+quad*4+r
#pragma unroll
    for (int nt = 0; nt < 4; ++nt) {
      const int r = nt * 16 + lrow;
      const short8 vb0 = *(const short8*)&Vs[buf][SW_IDX(r, quad)];
      const short8 vb1 = *(const short8*)&Vs[buf][SW_IDX(r, quad + 4)];
      o_acc[nt] = __builtin_amdgcn_mfma_f32_16x16x32_bf16(vb0, pa0, o_acc[nt], 0, 0, 0);
      o_acc[nt] = __builtin_amdgcn_mfma_f32_16x16x32_bf16(vb1, pa1, o_acc[nt], 0, 0, 0);
    }
    __syncthreads();   // drains vmcnt (next tile landed) + all reads of buf done
  }

  // epilogue: ctx [B,S,E] bf16, packed 8B stores
  const float inv = 1.f / lacc[0];
  const size_t rowb = ((size_t)b << 21) + ((size_t)(q0 + pr) << 10) + (h << 6);
#pragma unroll
  for (int nt = 0; nt < 4; ++nt) {
    uint2 u;
    u.x = pkbf(o_acc[nt][0] * inv, o_acc[nt][1] * inv);
    u.y = pkbf(o_acc[nt][2] * inv, o_acc[nt][3] * inv);
    *(uint2*)(ctx + rowb + nt * 16 + quad * 4) = u;
  }
}

// ---------------------------------------------------------------------------
extern "C" void kernel_launch(void* const* d_in, const int* in_sizes, int n_in,
                              void* d_out, int out_size, void* d_ws, size_t ws_size,
                              hipStream_t stream) {
  const float* q  = (const float*)d_in[0];
  const float* k  = (const float*)d_in[1];
  const float* v  = (const float*)d_in[2];
  // d_in[3] = causal mask (tril) — applied analytically, not read
  const float* Wq = (const float*)d_in[4];
  const float* bq = (const float*)d_in[5];
  const float* Wk = (const float*)d_in[6];
  const float* bk = (const float*)d_in[7];
  const float* Wv = (const float*)d_in[8];
  const float* bv = (const float*)d_in[9];
  const float* Wo = (const float*)d_in[10];
  const float* bo = (const float*)d_in[11];

  const size_t NTOK = (size_t)PB * PS * PE;   // 4,194,304 elems
  const size_t NW   = (size_t)PE * PE;        // 1,048,576 elems
  ushort* qh  = (ushort*)d_ws;
  ushort* kh  = qh + NTOK;
  ushort* vt  = kh + NTOK;
  ushort* qc  = vt + NTOK;
  ushort* kc  = qc + NTOK;
  ushort* vc  = kc + NTOK;
  ushort* wqc = vc + NTOK;
  ushort* wkc = wqc + NW;
  ushort* wvc = wkc + NW;
  ushort* woc = wvc + NW;
  ushort* ctx = qc;   // alias: qc is dead after qkv_kernel completes

  cvt_kernel<<<dim3(1024, 7), dim3(256), 0, stream>>>(
      q, k, v, Wq, Wk, Wv, Wo, qc, kc, vc, wqc, wkc, wvc, woc);
  qkv_kernel<<<dim3(32, 24), dim3(256), 0, stream>>>(
      qc, kc, vc, wqc, wkc, wvc, bq, bk, bv, qh, kh, vt);
  attn_kernel<<<dim3(32, 32), dim3(256), 0, stream>>>(qh, kh, vt, ctx);
  outproj_kernel<<<dim3(32, 8), dim3(256), 0, stream>>>(
      ctx, woc, bo, (float*)d_out);
}

// Round 16
// 215.574 us; speedup vs baseline: 1.0171x; 1.0171x over previous
//
#include <hip/hip_runtime.h>
#include <hip/hip_bf16.h>
#include <cstdint>

// Problem dims (fixed): B=2, S=2048, E=1024, H=16, D=64
#define PB 2
#define PS 2048
#define PE 1024
#define PH 16
#define PD 64

typedef __attribute__((ext_vector_type(8))) short short8;
typedef __attribute__((ext_vector_type(8))) ushort u16x8;
typedef __attribute__((ext_vector_type(4))) float f32x4;

static __device__ __forceinline__ float bf2f(ushort u) {
  return __uint_as_float(((unsigned)u) << 16);
}
static __device__ __forceinline__ ushort f2bf(float f) {
  unsigned u = __float_as_uint(f);
  u += 0x7fffu + ((u >> 16) & 1u);   // RNE
  return (ushort)(u >> 16);
}
// packed f32x2 -> bf16x2 (v_cvt_pk_bf16_f32 on gfx950 via HIP API)
static __device__ __forceinline__ unsigned pkbf(float a, float b) {
  __hip_bfloat162 h = __float22bfloat162_rn(make_float2(a, b));
  return *reinterpret_cast<unsigned*>(&h);
}
static __device__ __forceinline__ u16x8 cvt8(f32x4 a, f32x4 b) {
  union { unsigned u[4]; u16x8 v; } r;
  r.u[0] = pkbf(a[0], a[1]); r.u[1] = pkbf(a[2], a[3]);
  r.u[2] = pkbf(b[0], b[1]); r.u[3] = pkbf(b[2], b[3]);
  return r.v;
}

// CK-idiom async global->LDS 16B copy. LDS dest must be wave-uniform base.
static __device__ __forceinline__ void async16(void* lds, const void* g) {
  __attribute__((address_space(3))) unsigned* l =
      reinterpret_cast<__attribute__((address_space(3))) unsigned*>(
          reinterpret_cast<uintptr_t>(lds));
  const __attribute__((address_space(1))) unsigned* gp =
      reinterpret_cast<const __attribute__((address_space(1))) unsigned*>(
          reinterpret_cast<uintptr_t>(g));
  __builtin_amdgcn_global_load_lds(gp, l, 16, 0, 0);
}

// ---------------------------------------------------------------------------
// fp32 -> bf16 pre-conversion (x tensors + weights). blockIdx.y selects.
// 16 elems/thread.
// ---------------------------------------------------------------------------
__global__ __launch_bounds__(256)
void cvt_kernel(const float* __restrict__ s0, const float* __restrict__ s1,
                const float* __restrict__ s2, const float* __restrict__ s3,
                const float* __restrict__ s4, const float* __restrict__ s5,
                const float* __restrict__ s6,
                ushort* d0, ushort* d1, ushort* d2, ushort* d3, ushort* d4,
                ushort* d5, ushort* d6) {
  const int t = blockIdx.y;
  const float* src = t == 0 ? s0 : t == 1 ? s1 : t == 2 ? s2 : t == 3 ? s3
                   : t == 4 ? s4 : t == 5 ? s5 : s6;
  ushort* dst = t == 0 ? d0 : t == 1 ? d1 : t == 2 ? d2 : t == 3 ? d3
              : t == 4 ? d4 : t == 5 ? d5 : d6;
  const size_t n = (t < 3) ? (size_t)4194304 : (size_t)1048576;
  const size_t i0 = ((size_t)blockIdx.x * 256 + threadIdx.x) * 16;
  if (i0 >= n) return;
  const f32x4 a = *(const f32x4*)(src + i0);
  const f32x4 b = *(const f32x4*)(src + i0 + 4);
  const f32x4 c = *(const f32x4*)(src + i0 + 8);
  const f32x4 d = *(const f32x4*)(src + i0 + 12);
  *(u16x8*)(dst + i0) = cvt8(a, b);
  *(u16x8*)(dst + i0 + 8) = cvt8(c, d);
}

// ---------------------------------------------------------------------------
// GEMM core, bf16 A: BM=BN=128, BK=32, 4 waves 2x2, DEPTH-STAGE PIPELINE,
// SINGLE BARRIER PER ITER (R16): loop t = { vmcnt(ahead*4) -> s_barrier ->
// stage(t+DEPTH-1) -> compute(t) }. The old post-compute barrier (buf-reuse
// fence) is subsumed: stage at iter t writes buf (t-1)%D, whose last reader
// is compute(t-1) in iter t-1 — the single barrier at top of iter t
// separates them in every wave. ahead = min(31-t, DEPTH-2) tiles stay in
// flight across the barrier (tile t still has a (DEPTH-2)+1-iter window).
// Halves full-block sync points (64 -> 32 + prologue) — the measured qkv
// residual was sync slack, not pipe occupancy (R15 accounting).
// DEPTH=3: qkv (48KB, 3 blocks/CU). DEPTH=5: outproj (80KB, 1 block/CU).
// NOTE (R9): BM=64 regressed. NOTE (R11): K-phase rotation regressed —
// co-resident blocks' identical K order IS the L2 sharing; never desync.
// SWAP=false: acc[i][j] = C[m=x-rows i][n=W-rows j] (normal).
// SWAP=true : acc[i][j] = C[m=W-rows j][n=x-rows i] (transposed output).
// ---------------------------------------------------------------------------
template <bool SWAP, int DEPTH>
__device__ __forceinline__ void gemm_core(const ushort* __restrict__ A,
                                          const ushort* __restrict__ W,
                                          int m0, int n0,
                                          ushort* As, ushort* Bs,
                                          f32x4 acc[4][4]) {
  const int tid  = threadIdx.x;
  const int wave = tid >> 6;
  const int lane = tid & 63;
  const int quad = lane >> 4;
  const int lrow = lane & 15;
  const int wm = wave >> 1;
  const int wn = wave & 1;
  const int row0 = tid >> 2;
  const int kc8  = (tid & 3) * 8;

  auto stage = [&](int buf, int kt) {
    ushort* Ab = As + buf * 4096;
    ushort* Bb = Bs + buf * 4096;
    async16(Ab + (size_t)wave * 512,        A + (size_t)(m0 + row0)      * PE + kt + kc8);
    async16(Ab + 2048 + (size_t)wave * 512, A + (size_t)(m0 + row0 + 64) * PE + kt + kc8);
    async16(Bb + (size_t)wave * 512,        W + (size_t)(n0 + row0)      * PE + kt + kc8);
    async16(Bb + 2048 + (size_t)wave * 512, W + (size_t)(n0 + row0 + 64) * PE + kt + kc8);
  };

#pragma unroll
  for (int s = 0; s < DEPTH - 1; ++s) stage(s, s * 32);
  int cb = 0;                       // compute buffer = t % DEPTH (address-only)

  for (int t = 0; t < 32; ++t) {
    // tiles beyond t still in flight at this point (stages issue post-barrier)
    const int ahead = (31 - t < DEPTH - 2) ? (31 - t) : (DEPTH - 2);
    if      (ahead >= 3) asm volatile("s_waitcnt vmcnt(12)" ::: "memory");
    else if (ahead == 2) asm volatile("s_waitcnt vmcnt(8)"  ::: "memory");
    else if (ahead == 1) asm volatile("s_waitcnt vmcnt(4)"  ::: "memory");
    else                 asm volatile("s_waitcnt vmcnt(0)"  ::: "memory");
    __builtin_amdgcn_s_barrier();   // tile t resident for ALL waves; also the
                                    // buf-reuse fence for the stage below
    if (t + DEPTH - 1 < 32) {
      const int sb = (cb == 0) ? DEPTH - 1 : cb - 1;   // (t+DEPTH-1) % DEPTH
      stage(sb, (t + DEPTH - 1) * 32);
    }

    const ushort* Ab = As + cb * 4096;
    const ushort* Bb = Bs + cb * 4096;
    short8 af[4], bf[4];
#pragma unroll
    for (int i = 0; i < 4; ++i) {
      af[i] = *(const short8*)(Ab + (wm * 64 + i * 16 + lrow) * 32 + quad * 8);
      bf[i] = *(const short8*)(Bb + (wn * 64 + i * 16 + lrow) * 32 + quad * 8);
    }
#pragma unroll
    for (int i = 0; i < 4; ++i)
#pragma unroll
      for (int j = 0; j < 4; ++j) {
        if (SWAP)
          acc[i][j] = __builtin_amdgcn_mfma_f32_16x16x32_bf16(bf[j], af[i], acc[i][j], 0, 0, 0);
        else
          acc[i][j] = __builtin_amdgcn_mfma_f32_16x16x32_bf16(af[i], bf[j], acc[i][j], 0, 0, 0);
      }
    cb = (cb == DEPTH - 1) ? 0 : cb + 1;
  }
  __syncthreads();   // epilogue fence: all waves' LDS reads done (callers
                     // reuse the LDS; also drains any stray counts)
}

// ---------------------------------------------------------------------------
// Fused QKV projection (bf16 x, bf16 W). Q,K -> [B,H,S,D]; V -> [B,H,D,S']
// where S' applies the PV-native key permutation pi within each 64-key block
// (R14, harness-verified): pi(k) = (k&0x23)|((k&0xC)<<1)|((k&0x10)>>2).
// R15: pi-scatter absorbed in LDS (gemm LDS dead post-core), re-read
// row-wise -> 256B-contiguous global store runs. Q/K branch unchanged.
// Grid (x=m0, y=which*8+n0): n0-siblings share A-strip on one XCD's L2.
// ---------------------------------------------------------------------------
__global__ __launch_bounds__(256)
void qkv_kernel(const ushort* __restrict__ q, const ushort* __restrict__ k,
                const ushort* __restrict__ v,
                const ushort* __restrict__ Wq, const ushort* __restrict__ Wk,
                const ushort* __restrict__ Wv,
                const float* __restrict__ bq, const float* __restrict__ bk,
                const float* __restrict__ bv,
                ushort* __restrict__ qh, ushort* __restrict__ kh,
                ushort* __restrict__ vt) {
  __shared__ __align__(16) ushort SM[2 * 3 * 128 * 32];   // 48KB
  ushort* As = SM;
  ushort* Bs = SM + 3 * 128 * 32;
  const int which = blockIdx.y >> 3;
  const int n0 = (blockIdx.y & 7) * 128;
  const int m0 = blockIdx.x * 128;
  const ushort* A  = which == 0 ? q  : (which == 1 ? k  : v);
  const ushort* W  = which == 0 ? Wq : (which == 1 ? Wk : Wv);
  const float* bi  = which == 0 ? bq : (which == 1 ? bk : bv);

  const int lane = threadIdx.x & 63;
  const int wave = threadIdx.x >> 6;
  const int quad = lane >> 4, lrow = lane & 15;
  const int wm = wave >> 1, wn = wave & 1;

  f32x4 acc[4][4] = {};
  if (which == 2) {
    gemm_core<true, 3>(A, W, m0, n0, As, Bs, acc);
    // Phase 1: scatter into LDS [local_d][pi(local_s)] (XOR-swizzled
    // granules). gemm_core's trailing __syncthreads guarantees LDS is free.
#pragma unroll
    for (int j = 0; j < 4; ++j) {
#pragma unroll
      for (int i = 0; i < 4; ++i) {
        const int ls = wm * 64 + i * 16 + lrow;      // local_s 0..127
        const int k6 = ls & 63;                      // pi within 64-key block
        const int spp = (ls & 64) | (k6 & 0x23) | ((k6 & 0x0C) << 1) |
                        ((k6 & 0x10) >> 2);
#pragma unroll
        for (int r = 0; r < 4; ++r) {
          const int ld = wn * 64 + j * 16 + quad * 4 + r;  // local_d 0..127
          const int pos = (((spp >> 3) ^ (ld & 7)) << 3) | (spp & 7);
          SM[ld * 128 + pos] = f2bf(acc[i][j][r] + bi[n0 + ld]);
        }
      }
    }
    __syncthreads();
    // Phase 2: coalesced store — each d-row is 256B contiguous in vt.
    const int b = m0 >> 11, sbase = m0 & 2047;   // 128-blocks don't straddle b
    const int l16 = threadIdx.x & 15;
    const int r0  = threadIdx.x >> 4;            // 0..15
#pragma unroll
    for (int p = 0; p < 8; ++p) {
      const int ld = p * 16 + r0;
      const int dcol = n0 + ld;
      const int h = dcol >> 6, d = dcol & 63;
      const u16x8 vreg = *(const u16x8*)&SM[ld * 128 + ((l16 ^ (ld & 7)) << 3)];
      *(u16x8*)(vt + ((size_t)((b << 4) + h) << 17) + ((size_t)d << 11) +
                sbase + l16 * 8) = vreg;
    }
  } else {
    gemm_core<false, 3>(A, W, m0, n0, As, Bs, acc);
    ushort* Out = which == 0 ? qh : kh;
#pragma unroll
    for (int j = 0; j < 4; ++j) {
      const int col = n0 + wn * 64 + j * 16 + lrow;          // n in [0,1024)
      const float bias = bi[col];
      const int h = col >> 6, d = col & 63;
#pragma unroll
      for (int i = 0; i < 4; ++i)
#pragma unroll
        for (int r = 0; r < 4; ++r) {
          const int row = m0 + wm * 64 + i * 16 + quad * 4 + r;  // m in [0,4096)
          const int b = row >> 11, s = row & 2047;
          Out[((size_t)((b << 4) + h) << 17) + ((size_t)s << 6) + d] =
              f2bf(acc[i][j][r] + bias);
        }
    }
  }
}

// ---------------------------------------------------------------------------
// Output projection: out = ctx @ Wo^T + bo -> fp32 [4096,1024].
// Grid (x=m0 32, y=n0 8) = 1 block/CU -> DEPTH=5 (80KB LDS) does all the
// latency hiding in-block. BM=128 kept (R9: BM=64 regressed).
// ---------------------------------------------------------------------------
__global__ __launch_bounds__(256)
void outproj_kernel(const ushort* __restrict__ ctx, const ushort* __restrict__ Wo,
                    const float* __restrict__ bo, float* __restrict__ out) {
  __shared__ __align__(16) ushort As[5 * 128 * 32];
  __shared__ __align__(16) ushort Bs[5 * 128 * 32];
  const int n0 = blockIdx.y * 128;
  const int m0 = blockIdx.x * 128;

  f32x4 acc[4][4] = {};
  gemm_core<false, 5>(ctx, Wo, m0, n0, As, Bs, acc);

  const int lane = threadIdx.x & 63;
  const int wave = threadIdx.x >> 6;
  const int quad = lane >> 4, lrow = lane & 15;
  const int wm = wave >> 1, wn = wave & 1;
#pragma unroll
  for (int j = 0; j < 4; ++j) {
    const int col = n0 + wn * 64 + j * 16 + lrow;
    const float bias = bo[col];
#pragma unroll
    for (int i = 0; i < 4; ++i)
#pragma unroll
      for (int r = 0; r < 4; ++r) {
        const int row = m0 + wm * 64 + i * 16 + quad * 4 + r;
        out[((size_t)row << 10) + col] = acc[i][j][r] + bias;
      }
  }
}

// ---------------------------------------------------------------------------
// MFMA causal flash attention — R14/R15 version (P LDS round-trip deleted;
// harness-verified): qkv stores V^T with pi-permuted key columns, so the PV
// B-fragment equals the QK output register order after cvt_pk — P goes regs
// -> pkbf -> MFMA B-operand directly. No Ps buffer, 16 LDS ops/wave-tile.
// q-split, 4 blocks/CU, async K/V staging (pre-swizzled source, linear LDS
// dest, double-buffered, one __syncthreads per tile), NO setprio (m190/R9).
// Balance perm (R3), l via ones-MFMA (R3), SOFF in C-init (R2).
// ---------------------------------------------------------------------------
#define SW_IDX(r, g) (((r) << 6) + ((((g) ^ ((r) & 7))) << 3))
#define QSCALE 0.180336879f   /* 1/sqrt(64) * log2(e) */
#define SOFF 24.0f            /* static softmax offset (log2 domain) */

__global__ __launch_bounds__(256)
void attn_kernel(const ushort* __restrict__ qh, const ushort* __restrict__ kh,
                 const ushort* __restrict__ vt, ushort* __restrict__ ctx) {
  __shared__ __align__(16) ushort Ks[2][4096];
  __shared__ __align__(16) ushort Vs[2][4096];
  const int tid  = threadIdx.x;
  const int wave = tid >> 6;
  const int lane = tid & 63;
  const int quad = lane >> 4;
  const int lrow = lane & 15;
  const int bh = blockIdx.x, b = bh >> 4, h = bh & 15;
  const size_t base = (size_t)bh << 17;     // bh * S * D
  const int pr   = wave * 16 + lrow;        // this lane's q row in tile

  // balance permutation: CU-resident {y,y+8,y+16,y+24} sum to 62
  const int y  = blockIdx.y;
  const int qb = (y < 8) ? 31 - y : (y < 16) ? y - 8 : (y < 24) ? 39 - y : y - 16;
  const int q0 = qb * 64;

  // async staging geometry: wave w stages rows w*16..w*16+15 of K and V^T
  // (2 async16 calls each, 8 rows/call). Linear LDS dest + swizzled source.
  const int w16  = wave * 16;
  const int rl   = lane >> 3;                       // row within 8-row stripe
  const int gsw  = ((lane & 7) ^ rl) << 3;          // swizzled src granule
  auto stageKV = [&](int buf, int kt) {
    const ushort* k0 = kh + base + (size_t)(kt * 64 + w16 + rl) * 64 + gsw;
    const ushort* k1 = kh + base + (size_t)(kt * 64 + w16 + 8 + rl) * 64 + gsw;
    async16(&Ks[buf][w16 << 6],       k0);
    async16(&Ks[buf][(w16 + 8) << 6], k1);
    const ushort* v0 = vt + base + (size_t)(w16 + rl) * 2048 + kt * 64 + gsw;
    const ushort* v1 = vt + base + (size_t)(w16 + 8 + rl) * 2048 + kt * 64 + gsw;
    async16(&Vs[buf][w16 << 6],       v0);
    async16(&Vs[buf][(w16 + 8) << 6], v1);
  };

  // Q B-fragments in registers, scaled by 1/sqrt(D)*log2(e)
  short8 qf0, qf1;
  {
    const ushort* qp = qh + base + (size_t)(q0 + pr) * 64 + quad * 8;
    const u16x8 a = *(const u16x8*)qp;
    const u16x8 c = *(const u16x8*)(qp + 32);
#pragma unroll
    for (int j = 0; j < 8; ++j) {
      qf0[j] = (short)f2bf(bf2f(a[j]) * QSCALE);
      qf1[j] = (short)f2bf(bf2f(c[j]) * QSCALE);
    }
  }

  // all-ones bf16 A-fragment for the l row-sum MFMA
  short8 ones;
#pragma unroll
  for (int j = 0; j < 8; ++j) ones[j] = (short)0x3F80;

  f32x4 o_acc[4] = {};
  f32x4 lacc = {};   // P row-sum accumulator (every slot holds the same sum)

  stageKV(0, 0);
  __syncthreads();   // prologue drain: tile 0 resident

  for (int kt = 0; kt <= qb; ++kt) {
    const int buf = kt & 1;
    if (kt < qb) stageKV(buf ^ 1, kt + 1);   // in flight during compute

    // S^T = mfma(K, Q): lane -> q=pr, keys nt*16+quad*4+r; C-init = -SOFF
    f32x4 st[4];
#pragma unroll
    for (int nt = 0; nt < 4; ++nt) {
      const int r = nt * 16 + lrow;
      const short8 kb0 = *(const short8*)&Ks[buf][SW_IDX(r, quad)];
      const short8 kb1 = *(const short8*)&Ks[buf][SW_IDX(r, quad + 4)];
      st[nt] = (f32x4){-SOFF, -SOFF, -SOFF, -SOFF};
      st[nt] = __builtin_amdgcn_mfma_f32_16x16x32_bf16(kb0, qf0, st[nt], 0, 0, 0);
      st[nt] = __builtin_amdgcn_mfma_f32_16x16x32_bf16(kb1, qf1, st[nt], 0, 0, 0);
    }

    if (kt == qb) {    // causal mask on diagonal tile (local coords)
#pragma unroll
      for (int nt = 0; nt < 4; ++nt)
#pragma unroll
        for (int r = 0; r < 4; ++r)
          if (nt * 16 + quad * 4 + r > pr) st[nt][r] = -1e30f;
    }

    // softmax + pack DIRECTLY into PV B-fragments (PV-native key order via
    // qkv's pi-permuted V^T): no LDS, no cross-lane.
    union { unsigned u[8]; short8 v[2]; } pb;
#pragma unroll
    for (int nt = 0; nt < 4; ++nt) {
      const float p0 = exp2f(st[nt][0]);
      const float p1 = exp2f(st[nt][1]);
      const float p2 = exp2f(st[nt][2]);
      const float p3 = exp2f(st[nt][3]);
      pb.u[nt * 2]     = pkbf(p0, p1);
      pb.u[nt * 2 + 1] = pkbf(p2, p3);
    }
    const short8 pa0 = pb.v[0];
    const short8 pa1 = pb.v[1];

    // l row-sum on the MFMA pipe: A=ones -> out[q][*] = sum_k P[q][k]
    lacc = __builtin_amdgcn_mfma_f32_16x16x32_bf16(ones, pa0, lacc, 0, 0, 0);
    lacc = __builtin_amdgcn_mfma_f32_16x16x32_bf16(ones, pa1, lacc, 0, 0, 0);

    // PV: O^T = mfma(V^T, P): lane -> q=pr, d = nt*16+quad*4+r
#pragma unroll
    for (int nt = 0; nt < 4; ++nt) {
      const int r = nt * 16 + lrow;
      const short8 vb0 = *(const short8*)&Vs[buf][SW_IDX(r, quad)];
      const short8 vb1 = *(const short8*)&Vs[buf][SW_IDX(r, quad + 4)];
      o_acc[nt] = __builtin_amdgcn_mfma_f32_16x16x32_bf16(vb0, pa0, o_acc[nt], 0, 0, 0);
      o_acc[nt] = __builtin_amdgcn_mfma_f32_16x16x32_bf16(vb1, pa1, o_acc[nt], 0, 0, 0);
    }
    __syncthreads();   // drains vmcnt (next tile landed) + all reads of buf done
  }

  // epilogue: ctx [B,S,E] bf16, packed 8B stores
  const float inv = 1.f / lacc[0];
  const size_t rowb = ((size_t)b << 21) + ((size_t)(q0 + pr) << 10) + (h << 6);
#pragma unroll
  for (int nt = 0; nt < 4; ++nt) {
    uint2 u;
    u.x = pkbf(o_acc[nt][0] * inv, o_acc[nt][1] * inv);
    u.y = pkbf(o_acc[nt][2] * inv, o_acc[nt][3] * inv);
    *(uint2*)(ctx + rowb + nt * 16 + quad * 4) = u;
  }
}

// ---------------------------------------------------------------------------
extern "C" void kernel_launch(void* const* d_in, const int* in_sizes, int n_in,
                              void* d_out, int out_size, void* d_ws, size_t ws_size,
                              hipStream_t stream) {
  const float* q  = (const float*)d_in[0];
  const float* k  = (const float*)d_in[1];
  const float* v  = (const float*)d_in[2];
  // d_in[3] = causal mask (tril) — applied analytically, not read
  const float* Wq = (const float*)d_in[4];
  const float* bq = (const float*)d_in[5];
  const float* Wk = (const float*)d_in[6];
  const float* bk = (const float*)d_in[7];
  const float* Wv = (const float*)d_in[8];
  const float* bv = (const float*)d_in[9];
  const float* Wo = (const float*)d_in[10];
  const float* bo = (const float*)d_in[11];

  const size_t NTOK = (size_t)PB * PS * PE;   // 4,194,304 elems
  const size_t NW   = (size_t)PE * PE;        // 1,048,576 elems
  ushort* qh  = (ushort*)d_ws;
  ushort* kh  = qh + NTOK;
  ushort* vt  = kh + NTOK;
  ushort* qc  = vt + NTOK;
  ushort* kc  = qc + NTOK;
  ushort* vc  = kc + NTOK;
  ushort* wqc = vc + NTOK;
  ushort* wkc = wqc + NW;
  ushort* wvc = wkc + NW;
  ushort* woc = wvc + NW;
  ushort* ctx = qc;   // alias: qc is dead after qkv_kernel completes

  cvt_kernel<<<dim3(1024, 7), dim3(256), 0, stream>>>(
      q, k, v, Wq, Wk, Wv, Wo, qc, kc, vc, wqc, wkc, wvc, woc);
  qkv_kernel<<<dim3(32, 24), dim3(256), 0, stream>>>(
      qc, kc, vc, wqc, wkc, wvc, bq, bk, bv, qh, kh, vt);
  attn_kernel<<<dim3(32, 32), dim3(256), 0, stream>>>(qh, kh, vt, ctx);
  outproj_kernel<<<dim3(32, 8), dim3(256), 0, stream>>>(
      ctx, woc, bo, (float*)d_out);
}